// Round 2
// baseline (140.169 us; speedup 1.0000x reference)
//
#include <hip/hip_runtime.h>
#include <hip/hip_fp16.h>

typedef _Float16 half8  __attribute__((ext_vector_type(8)));
typedef _Float16 half4v __attribute__((ext_vector_type(4)));
typedef float    f32x4  __attribute__((ext_vector_type(4)));

#define MFMA_F16 __builtin_amdgcn_mfma_f32_16x16x32_f16

// ---------------- kernel 0: W_q|W_k|W_v f32 -> concat f16 [384][1024] ----------------
__global__ __launch_bounds__(256) void wconv_k(const float* __restrict__ wq,
                                               const float* __restrict__ wk,
                                               const float* __restrict__ wv,
                                               _Float16* __restrict__ wh) {
    int i = (blockIdx.x * 256 + threadIdx.x) * 8;   // 393216 total elems
    const float* src; int off;
    if (i < 131072)      { src = wq; off = i; }
    else if (i < 262144) { src = wk; off = i - 131072; }
    else                 { src = wv; off = i - 262144; }
    float4 a = *(const float4*)(src + off);
    float4 b = *(const float4*)(src + off + 4);
    half8 h;
    h[0]=(_Float16)a.x; h[1]=(_Float16)a.y; h[2]=(_Float16)a.z; h[3]=(_Float16)a.w;
    h[4]=(_Float16)b.x; h[5]=(_Float16)b.y; h[6]=(_Float16)b.z; h[7]=(_Float16)b.w;
    *(half8*)(wh + i) = h;
}

// ---------------- kernel 1: fused QKV projection (pipelined) ----------------
// 256 blocks x 512 threads (8 waves, 2m x 4n). Block: 64 rows x 384 cols, K-step 32.
// x prefetched depth-4 in regs; W prefetched depth-1 in regs; LDS x-slab double-buffered.
__global__ __launch_bounds__(512) void qkv_k(const float* __restrict__ x,
                                             const _Float16* __restrict__ wh,
                                             _Float16* __restrict__ qh,
                                             _Float16* __restrict__ kh,
                                             _Float16* __restrict__ vth) {
    __shared__ _Float16 xs[2][64 * 40];
    int tid = threadIdx.x;
    int w = tid >> 6, l = tid & 63;
    int wm = w >> 2, wn = w & 3;
    int fr = l & 15, fq = l >> 4;
    int row0 = blockIdx.x * 64;
    int srow = tid >> 3, sc4 = (tid & 7) * 4;
    const float* xg = x + (row0 + srow) * 1024 + sc4;
    const _Float16* wgb = wh + (wn * 96 + fr) * 1024 + fq * 8;

    f32x4 acc[2][6] = {};
    float4 xa[4];
    half8 wf[2][6];

    // prologue: stage x[0] directly, preload x[1..4], W[0]
    {
        float4 t = *(const float4*)(xg);
        half4v hv;
        hv[0]=(_Float16)t.x; hv[1]=(_Float16)t.y; hv[2]=(_Float16)t.z; hv[3]=(_Float16)t.w;
        *(half4v*)(&xs[0][srow * 40 + sc4]) = hv;
    }
    xa[1] = *(const float4*)(xg + 32);
    xa[2] = *(const float4*)(xg + 64);
    xa[3] = *(const float4*)(xg + 96);
    xa[0] = *(const float4*)(xg + 128);
#pragma unroll
    for (int nf = 0; nf < 6; ++nf) wf[0][nf] = *(const half8*)(wgb + nf * 16384);
    __syncthreads();

#pragma unroll 4
    for (int kk = 0; kk < 32; ++kk) {
        int cur = kk & 1, nb = cur ^ 1;
        int xslot = (kk + 1) & 3;
        if (kk < 31) {                    // convert+write x[kk+1] -> slab nb
            float4 t = xa[xslot];
            half4v hv;
            hv[0]=(_Float16)t.x; hv[1]=(_Float16)t.y; hv[2]=(_Float16)t.z; hv[3]=(_Float16)t.w;
            *(half4v*)(&xs[nb][srow * 40 + sc4]) = hv;
        }
        if (kk < 27)                      // issue global load x[kk+5]
            xa[xslot] = *(const float4*)(xg + (kk + 5) * 32);
        if (kk < 31) {                    // prefetch W[kk+1]
#pragma unroll
            for (int nf = 0; nf < 6; ++nf)
                wf[nb][nf] = *(const half8*)(wgb + nf * 16384 + (kk + 1) * 32);
        }
        half8 af[2];
#pragma unroll
        for (int mf = 0; mf < 2; ++mf)
            af[mf] = *(const half8*)(&xs[cur][(wm * 32 + mf * 16 + fr) * 40 + fq * 8]);
#pragma unroll
        for (int mf = 0; mf < 2; ++mf)
#pragma unroll
            for (int nf = 0; nf < 6; ++nf)
                acc[mf][nf] = MFMA_F16(af[mf], wf[cur][nf], acc[mf][nf], 0, 0, 0);
        __syncthreads();
    }

    // epilogue: row = row0 + wm*32 + mf*16 + fq*4 + r, col = wn*96 + nf*16 + fr
#pragma unroll
    for (int nf = 0; nf < 6; ++nf) {
        int n0 = wn * 96 + nf * 16 + fr;
#pragma unroll
        for (int mf = 0; mf < 2; ++mf) {
#pragma unroll
            for (int r = 0; r < 4; ++r) {
                int m = row0 + wm * 32 + mf * 16 + fq * 4 + r;
                _Float16 v = (_Float16)acc[mf][nf][r];
                if (n0 < 128)       qh[m * 128 + n0] = v;
                else if (n0 < 256)  kh[m * 128 + (n0 - 128)] = v;
                else                vth[(((m >> 11) << 7) + (n0 - 256)) * 2048 + (m & 2047)] = v;
            }
        }
    }
}

// ---------------- kernel 2: causal flash attention, split-KV ----------------
// 640 blocks x 256 threads (4 waves). Block = (b = bid&7, q-tile qt (64 rows), kv-chunk c).
// Chunk = 8 kv-tiles of 64 (512 kv). Writes per-chunk normalized partial O (f16) + (m,l) f32.
__global__ __launch_bounds__(256) void attn_k(const _Float16* __restrict__ qh,
                                              const _Float16* __restrict__ kh,
                                              const _Float16* __restrict__ vth,
                                              _Float16* __restrict__ part,
                                              float* __restrict__ stats) {
    __shared__ _Float16 ks[64 * 136];
    __shared__ _Float16 vs[128 * 72];
    __shared__ _Float16 ps[64 * 72];

    int bid = blockIdx.x;
    int b = bid & 7;
    int w80 = bid >> 3;
    int qt, c;
    if (w80 < 8)       { qt = w80;                 c = 0; }
    else if (w80 < 24) { qt = 8  + ((w80 - 8) >> 1);  c = (w80 - 8) & 1; }
    else if (w80 < 48) { qt = 16 + (w80 - 24) / 3;    c = (w80 - 24) % 3; }
    else               { qt = 24 + ((w80 - 48) >> 2); c = (w80 - 48) & 3; }
    int j0 = c * 8;
    int j1 = j0 + 8 < qt + 1 ? j0 + 8 : qt + 1;

    int tid = threadIdx.x, w = tid >> 6, l = tid & 63;
    int fr = l & 15, fq = l >> 4;

    half8 qf[4];
    const _Float16* qp = qh + ((b * 2048 + qt * 64 + w * 16 + fr) << 7);
#pragma unroll
    for (int cc = 0; cc < 4; ++cc) qf[cc] = *(const half8*)(qp + cc * 32 + fq * 8);

    f32x4 acc[8] = {};
    float mrow[4], lrow[4];
#pragma unroll
    for (int r = 0; r < 4; ++r) { mrow[r] = -1e30f; lrow[r] = 0.0f; }

    for (int j = j0; j < j1; ++j) {
#pragma unroll
        for (int u = 0; u < 4; ++u) {
            int ci = tid + u * 256;
            int kr = ci >> 4, c16 = ci & 15;
            uint4 kd = *(const uint4*)(kh + (((b << 11) + (j << 6) + kr) << 7) + c16 * 8);
            *(uint4*)(&ks[kr * 136 + c16 * 8]) = kd;
            int vd = ci >> 3, c8 = ci & 7;
            uint4 vv = *(const uint4*)(vth + ((((b << 7) + vd) << 11) + (j << 6) + c8 * 8));
            *(uint4*)(&vs[vd * 72 + c8 * 8]) = vv;
        }
        __syncthreads();

        f32x4 s[4] = {};
#pragma unroll
        for (int n = 0; n < 4; ++n) {
#pragma unroll
            for (int cc = 0; cc < 4; ++cc) {
                half8 kf = *(const half8*)(&ks[(n * 16 + fr) * 136 + cc * 32 + fq * 8]);
                s[n] = MFMA_F16(qf[cc], kf, s[n], 0, 0, 0);
            }
        }
        const float sc = 0.088388347648318447f;  // 1/sqrt(128)
        if (j == qt) {
#pragma unroll
            for (int n = 0; n < 4; ++n)
#pragma unroll
                for (int r = 0; r < 4; ++r) {
                    int qrow = w * 16 + fq * 4 + r;
                    int kcol = n * 16 + fr;
                    float v = s[n][r] * sc;
                    s[n][r] = (kcol > qrow) ? -1e30f : v;
                }
        } else {
#pragma unroll
            for (int n = 0; n < 4; ++n)
#pragma unroll
                for (int r = 0; r < 4; ++r) s[n][r] *= sc;
        }

        float mx[4];
#pragma unroll
        for (int r = 0; r < 4; ++r)
            mx[r] = fmaxf(fmaxf(s[0][r], s[1][r]), fmaxf(s[2][r], s[3][r]));
#pragma unroll
        for (int off = 1; off < 16; off <<= 1)
#pragma unroll
            for (int r = 0; r < 4; ++r) mx[r] = fmaxf(mx[r], __shfl_xor(mx[r], off));
        float al[4];
#pragma unroll
        for (int r = 0; r < 4; ++r) {
            float nm = fmaxf(mrow[r], mx[r]);
            al[r] = __expf(mrow[r] - nm);
            mrow[r] = nm;
        }
        float rs[4] = {0.f, 0.f, 0.f, 0.f};
#pragma unroll
        for (int n = 0; n < 4; ++n)
#pragma unroll
            for (int r = 0; r < 4; ++r) {
                float p = __expf(s[n][r] - mrow[r]);
                s[n][r] = p;
                rs[r] += p;
            }
#pragma unroll
        for (int off = 1; off < 16; off <<= 1)
#pragma unroll
            for (int r = 0; r < 4; ++r) rs[r] += __shfl_xor(rs[r], off);
#pragma unroll
        for (int r = 0; r < 4; ++r) lrow[r] = lrow[r] * al[r] + rs[r];
#pragma unroll
        for (int dt = 0; dt < 8; ++dt)
#pragma unroll
            for (int r = 0; r < 4; ++r) acc[dt][r] *= al[r];

#pragma unroll
        for (int n = 0; n < 4; ++n)
#pragma unroll
            for (int r = 0; r < 4; ++r)
                ps[(w * 16 + fq * 4 + r) * 72 + n * 16 + fr] = (_Float16)s[n][r];

        half8 pa[2];
#pragma unroll
        for (int c2 = 0; c2 < 2; ++c2)
            pa[c2] = *(const half8*)(&ps[(w * 16 + fr) * 72 + c2 * 32 + fq * 8]);
#pragma unroll
        for (int dt = 0; dt < 8; ++dt)
#pragma unroll
            for (int c2 = 0; c2 < 2; ++c2) {
                half8 vf = *(const half8*)(&vs[(dt * 16 + fr) * 72 + c2 * 32 + fq * 8]);
                acc[dt] = MFMA_F16(pa[c2], vf, acc[dt], 0, 0, 0);
            }
        __syncthreads();
    }

    // write per-chunk partial: O_c = acc / l (f16), stats (m, l) f32
    int p = (b * 32 + qt) * 4 + c;
    float inv[4];
#pragma unroll
    for (int r = 0; r < 4; ++r) inv[r] = 1.0f / lrow[r];
    _Float16* op = part + p * 8192 + ((w * 16 + fq * 4) << 7) + fr;
#pragma unroll
    for (int dt = 0; dt < 8; ++dt)
#pragma unroll
        for (int r = 0; r < 4; ++r)
            op[r * 128 + dt * 16] = (_Float16)(acc[dt][r] * inv[r]);
    if (fr == 0) {
#pragma unroll
        for (int r = 0; r < 4; ++r) {
            int ridx = p * 64 + w * 16 + fq * 4 + r;
            stats[ridx * 2]     = mrow[r];
            stats[ridx * 2 + 1] = lrow[r];
        }
    }
}

// ---------------- kernel 3: combine split-KV partials ----------------
// 256 blocks (b, qt) x 256 threads. out = sum_c w_c O_c / sum_c w_c,  w_c = exp(m_c-m*) l_c
__global__ __launch_bounds__(256) void comb_k(const _Float16* __restrict__ part,
                                              const float* __restrict__ stats,
                                              float* __restrict__ out) {
    int bid = blockIdx.x;
    int b = bid & 7, qt = bid >> 3;
    int nc = (qt + 8) >> 3;
    int p0 = (b * 32 + qt) * 4;
    int tid = threadIdx.x;

#pragma unroll
    for (int u = 0; u < 8; ++u) {
        int g = tid + u * 256;            // float4 granule
        int row = g >> 5;
        int c4 = (g & 31) * 4;
        float mstar = -1e30f, mv[4], lv[4];
#pragma unroll
        for (int cc = 0; cc < 4; ++cc) {
            if (cc < nc) {
                mv[cc] = stats[((p0 + cc) * 64 + row) * 2];
                lv[cc] = stats[((p0 + cc) * 64 + row) * 2 + 1];
                mstar = fmaxf(mstar, mv[cc]);
            }
        }
        float den = 0.f, wc[4];
#pragma unroll
        for (int cc = 0; cc < 4; ++cc) {
            if (cc < nc) { wc[cc] = __expf(mv[cc] - mstar) * lv[cc]; den += wc[cc]; }
            else wc[cc] = 0.f;
        }
        float a0 = 0.f, a1 = 0.f, a2 = 0.f, a3 = 0.f;
#pragma unroll
        for (int cc = 0; cc < 4; ++cc) {
            if (cc < nc) {
                half4v h = *(const half4v*)(part + (p0 + cc) * 8192 + row * 128 + c4);
                a0 += wc[cc] * (float)h[0];
                a1 += wc[cc] * (float)h[1];
                a2 += wc[cc] * (float)h[2];
                a3 += wc[cc] * (float)h[3];
            }
        }
        float id = 1.0f / den;
        float4 o; o.x = a0 * id; o.y = a1 * id; o.z = a2 * id; o.w = a3 * id;
        *(float4*)(out + ((b * 2048 + qt * 64 + row) << 7) + c4) = o;
    }
}

extern "C" void kernel_launch(void* const* d_in, const int* in_sizes, int n_in,
                              void* d_out, int out_size, void* d_ws, size_t ws_size,
                              hipStream_t stream) {
    const float* x  = (const float*)d_in[0];
    const float* wq = (const float*)d_in[1];
    const float* wk = (const float*)d_in[2];
    const float* wv = (const float*)d_in[3];

    char* ws = (char*)d_ws;
    _Float16* wh   = (_Float16*)(ws);                    // 768 KB
    _Float16* qhp  = (_Float16*)(ws + (1u  << 20));      // 4 MB
    _Float16* khp  = (_Float16*)(ws + (5u  << 20));      // 4 MB
    _Float16* vtp  = (_Float16*)(ws + (9u  << 20));      // 4 MB
    _Float16* part = (_Float16*)(ws + (13u << 20));      // 16.78 MB
    float*    stat = (float*)   (ws + (30u << 20));      // 512 KB

    wconv_k<<<192, 256, 0, stream>>>(wq, wk, wv, wh);
    qkv_k<<<256, 512, 0, stream>>>(x, wh, qhp, khp, vtp);
    attn_k<<<640, 256, 0, stream>>>(qhp, khp, vtp, part, stat);
    comb_k<<<256, 256, 0, stream>>>(part, stat, (float*)d_out);
}

// Round 3
// 112.732 us; speedup vs baseline: 1.2434x; 1.2434x over previous
//
#include <hip/hip_runtime.h>
#include <hip/hip_fp16.h>

typedef _Float16 half8  __attribute__((ext_vector_type(8)));
typedef _Float16 half4v __attribute__((ext_vector_type(4)));
typedef float    f32x4  __attribute__((ext_vector_type(4)));

#define MFMA_F16 __builtin_amdgcn_mfma_f32_16x16x32_f16

// ---------------- kernel 0: W_q|W_k|W_v f32 -> concat f16 [384][1024] ----------------
__global__ __launch_bounds__(256) void wconv_k(const float* __restrict__ wq,
                                               const float* __restrict__ wk,
                                               const float* __restrict__ wv,
                                               _Float16* __restrict__ wh) {
    int i = (blockIdx.x * 256 + threadIdx.x) * 8;   // 393216 total elems
    const float* src; int off;
    if (i < 131072)      { src = wq; off = i; }
    else if (i < 262144) { src = wk; off = i - 131072; }
    else                 { src = wv; off = i - 262144; }
    float4 a = *(const float4*)(src + off);
    float4 b = *(const float4*)(src + off + 4);
    half8 h;
    h[0]=(_Float16)a.x; h[1]=(_Float16)a.y; h[2]=(_Float16)a.z; h[3]=(_Float16)a.w;
    h[4]=(_Float16)b.x; h[5]=(_Float16)b.y; h[6]=(_Float16)b.z; h[7]=(_Float16)b.w;
    *(half8*)(wh + i) = h;
}

// ---------------- kernel 1: fused QKV projection ----------------
// grid 512: rb=bid>>1 (64-row group), cb=bid&1 (192-col half). 256 thr = 4 waves.
// Wave w: 64 rows x 48 cols (cols cb*192 + 48w). K-step 128 (8 barriers total).
__global__ __launch_bounds__(256, 2) void qkv_k(const float* __restrict__ x,
                                                const _Float16* __restrict__ wh,
                                                _Float16* __restrict__ qh,
                                                _Float16* __restrict__ kh,
                                                _Float16* __restrict__ vth) {
    __shared__ _Float16 xs[2][64 * 136];   // 64 rows x 128 k, stride 136 (2-way alias = free)
    const int tid = threadIdx.x;
    const int w = tid >> 6, l = tid & 63;
    const int fr = l & 15, fq = l >> 4;
    const int rb = blockIdx.x >> 1, cb = blockIdx.x & 1;
    const int row0 = rb * 64;
    const int c0 = cb * 192 + w * 48;

    const int srow = tid >> 2, sg = tid & 3;          // stage: row, 4-float group
    const float* xg = x + (row0 + srow) * 1024 + sg * 4;
    const _Float16* wgb = wh + (c0 + fr) * 1024 + fq * 8;

    f32x4 acc[4][3] = {};
    float4 xa[8];
    half8 wf[2][3];

    // prologue: tile 0 -> LDS0, issue tile-1 loads, W substep-0
#pragma unroll
    for (int i = 0; i < 8; ++i) xa[i] = *(const float4*)(xg + i * 16);
#pragma unroll
    for (int i = 0; i < 8; ++i) {
        float4 t = xa[i]; half4v hv;
        hv[0]=(_Float16)t.x; hv[1]=(_Float16)t.y; hv[2]=(_Float16)t.z; hv[3]=(_Float16)t.w;
        *(half4v*)(&xs[0][srow * 136 + sg * 4 + i * 16]) = hv;
    }
#pragma unroll
    for (int i = 0; i < 8; ++i) xa[i] = *(const float4*)(xg + 128 + i * 16);
#pragma unroll
    for (int nf = 0; nf < 3; ++nf) wf[0][nf] = *(const half8*)(wgb + nf * 16384);
    __syncthreads();

    int cur = 0;
    for (int kt = 0; kt < 8; ++kt) {
        if (kt < 7) {                         // write tile kt+1 (regs) -> other buffer
#pragma unroll
            for (int i = 0; i < 8; ++i) {
                float4 t = xa[i]; half4v hv;
                hv[0]=(_Float16)t.x; hv[1]=(_Float16)t.y; hv[2]=(_Float16)t.z; hv[3]=(_Float16)t.w;
                *(half4v*)(&xs[cur ^ 1][srow * 136 + sg * 4 + i * 16]) = hv;
            }
            if (kt < 6) {                     // issue loads for tile kt+2
#pragma unroll
                for (int i = 0; i < 8; ++i)
                    xa[i] = *(const float4*)(xg + (kt + 2) * 128 + i * 16);
            }
        }
#pragma unroll
        for (int s = 0; s < 4; ++s) {         // 4 x K-32 substeps on xs[cur]
            const int ss = kt * 4 + s;
            const int csw = ss & 1;
            if (ss + 1 < 32) {
#pragma unroll
                for (int nf = 0; nf < 3; ++nf)
                    wf[csw ^ 1][nf] = *(const half8*)(wgb + nf * 16384 + (ss + 1) * 32);
            }
            half8 af[4];
#pragma unroll
            for (int mf = 0; mf < 4; ++mf)
                af[mf] = *(const half8*)(&xs[cur][(mf * 16 + fr) * 136 + s * 32 + fq * 8]);
#pragma unroll
            for (int mf = 0; mf < 4; ++mf)
#pragma unroll
                for (int nf = 0; nf < 3; ++nf)
                    acc[mf][nf] = MFMA_F16(af[mf], wf[csw][nf], acc[mf][nf], 0, 0, 0);
        }
        __syncthreads();
        cur ^= 1;
    }

    // epilogue: row = row0 + mf*16 + fq*4 + r, col = c0 + nf*16 + fr
#pragma unroll
    for (int nf = 0; nf < 3; ++nf) {
        int n0 = c0 + nf * 16 + fr;
#pragma unroll
        for (int mf = 0; mf < 4; ++mf) {
            int mb = row0 + mf * 16 + fq * 4;
            if (n0 < 128) {
#pragma unroll
                for (int r = 0; r < 4; ++r) qh[(mb + r) * 128 + n0] = (_Float16)acc[mf][nf][r];
            } else if (n0 < 256) {
#pragma unroll
                for (int r = 0; r < 4; ++r) kh[(mb + r) * 128 + (n0 - 128)] = (_Float16)acc[mf][nf][r];
            } else {
                half4v pv;
#pragma unroll
                for (int r = 0; r < 4; ++r) pv[r] = (_Float16)acc[mf][nf][r];
                *(half4v*)(&vth[((mb >> 11) * 128 + (n0 - 256)) * 2048 + (mb & 2047)]) = pv;
            }
        }
    }
}

// ---------------- kernel 2: causal flash attention, split-KV (chunk = 4 kv-tiles) ----------------
// 1152 blocks x 256 threads (4 waves). bid -> (b, qt, c) via variable chunk count nc(qt)=(qt>>2)+1.
__global__ __launch_bounds__(256, 3) void attn_k(const _Float16* __restrict__ qh,
                                                 const _Float16* __restrict__ kh,
                                                 const _Float16* __restrict__ vth,
                                                 _Float16* __restrict__ part,
                                                 float* __restrict__ stats) {
    __shared__ _Float16 ks[64 * 136];
    __shared__ _Float16 vs[128 * 72];
    __shared__ _Float16 ps[64 * 72];

    int bid = blockIdx.x;
    int b = bid / 144;
    int idx = bid - b * 144;
    int qt = 0;
    for (;;) { int nc = (qt >> 2) + 1; if (idx < nc) break; idx -= nc; ++qt; }
    int c = idx;
    int j0 = c * 4;
    int j1 = j0 + 4 < qt + 1 ? j0 + 4 : qt + 1;

    int tid = threadIdx.x, w = tid >> 6, l = tid & 63;
    int fr = l & 15, fq = l >> 4;

    half8 qf[4];
    const _Float16* qp = qh + ((b * 2048 + qt * 64 + w * 16 + fr) << 7);
#pragma unroll
    for (int cc = 0; cc < 4; ++cc) qf[cc] = *(const half8*)(qp + cc * 32 + fq * 8);

    uint4 kreg[4], vreg[4];
#define LOAD_TILE(j) do {                                                                 \
    _Pragma("unroll")                                                                     \
    for (int u = 0; u < 4; ++u) {                                                         \
        int ci = tid + u * 256;                                                           \
        kreg[u] = *(const uint4*)(kh + (((b << 11) + ((j) << 6) + (ci >> 4)) << 7) + (ci & 15) * 8); \
        vreg[u] = *(const uint4*)(vth + ((((b << 7) + (ci >> 3)) << 11) + ((j) << 6) + (ci & 7) * 8)); \
    } } while (0)
#define WRITE_TILE() do {                                                                 \
    _Pragma("unroll")                                                                     \
    for (int u = 0; u < 4; ++u) {                                                         \
        int ci = tid + u * 256;                                                           \
        *(uint4*)(&ks[(ci >> 4) * 136 + (ci & 15) * 8]) = kreg[u];                        \
        *(uint4*)(&vs[(ci >> 3) * 72 + (ci & 7) * 8]) = vreg[u];                          \
    } } while (0)

    f32x4 acc[8] = {};
    float mrow[4], lrow[4];
#pragma unroll
    for (int r = 0; r < 4; ++r) { mrow[r] = -1e30f; lrow[r] = 0.0f; }

    LOAD_TILE(j0);
    WRITE_TILE();
    if (j0 + 1 < j1) LOAD_TILE(j0 + 1);
    __syncthreads();

    for (int j = j0; j < j1; ++j) {
        // S = Q K^T; D layout: col = fr (kv), row = fq*4+r (q)
        f32x4 s[4] = {};
#pragma unroll
        for (int n = 0; n < 4; ++n) {
#pragma unroll
            for (int cc = 0; cc < 4; ++cc) {
                half8 kf = *(const half8*)(&ks[(n * 16 + fr) * 136 + cc * 32 + fq * 8]);
                s[n] = MFMA_F16(qf[cc], kf, s[n], 0, 0, 0);
            }
        }
        const float sc = 0.088388347648318447f;  // 1/sqrt(128)
        if (j == qt) {
#pragma unroll
            for (int n = 0; n < 4; ++n)
#pragma unroll
                for (int r = 0; r < 4; ++r) {
                    int qrow = w * 16 + fq * 4 + r;
                    int kcol = n * 16 + fr;
                    float v = s[n][r] * sc;
                    s[n][r] = (kcol > qrow) ? -1e30f : v;
                }
        } else {
#pragma unroll
            for (int n = 0; n < 4; ++n)
#pragma unroll
                for (int r = 0; r < 4; ++r) s[n][r] *= sc;
        }

        float mx[4];
#pragma unroll
        for (int r = 0; r < 4; ++r)
            mx[r] = fmaxf(fmaxf(s[0][r], s[1][r]), fmaxf(s[2][r], s[3][r]));
#pragma unroll
        for (int off = 1; off < 16; off <<= 1)
#pragma unroll
            for (int r = 0; r < 4; ++r) mx[r] = fmaxf(mx[r], __shfl_xor(mx[r], off));
        float al[4];
#pragma unroll
        for (int r = 0; r < 4; ++r) {
            float nm = fmaxf(mrow[r], mx[r]);
            al[r] = __expf(mrow[r] - nm);
            mrow[r] = nm;
        }
        float rs[4] = {0.f, 0.f, 0.f, 0.f};
#pragma unroll
        for (int n = 0; n < 4; ++n)
#pragma unroll
            for (int r = 0; r < 4; ++r) {
                float p = __expf(s[n][r] - mrow[r]);
                s[n][r] = p;
                rs[r] += p;
            }
#pragma unroll
        for (int off = 1; off < 16; off <<= 1)
#pragma unroll
            for (int r = 0; r < 4; ++r) rs[r] += __shfl_xor(rs[r], off);
#pragma unroll
        for (int r = 0; r < 4; ++r) lrow[r] = lrow[r] * al[r] + rs[r];
#pragma unroll
        for (int dt = 0; dt < 8; ++dt)
#pragma unroll
            for (int r = 0; r < 4; ++r) acc[dt][r] *= al[r];

        // P -> per-wave LDS region, then PV
#pragma unroll
        for (int n = 0; n < 4; ++n)
#pragma unroll
            for (int r = 0; r < 4; ++r)
                ps[(w * 16 + fq * 4 + r) * 72 + n * 16 + fr] = (_Float16)s[n][r];

        half8 pa[2];
#pragma unroll
        for (int c2 = 0; c2 < 2; ++c2)
            pa[c2] = *(const half8*)(&ps[(w * 16 + fr) * 72 + c2 * 32 + fq * 8]);
#pragma unroll
        for (int dt = 0; dt < 8; ++dt)
#pragma unroll
            for (int c2 = 0; c2 < 2; ++c2) {
                half8 vf = *(const half8*)(&vs[(dt * 16 + fr) * 72 + c2 * 32 + fq * 8]);
                acc[dt] = MFMA_F16(pa[c2], vf, acc[dt], 0, 0, 0);
            }

        if (j + 1 < j1) {
            __syncthreads();          // everyone done reading ks/vs
            WRITE_TILE();             // regs hold tile j+1 (issued >= 1 compute phase ago)
            if (j + 2 < j1) LOAD_TILE(j + 2);
            __syncthreads();          // tiles ready
        }
    }

    // per-chunk partial: O_c = acc / l (f16) at block index bid, stats (m,l) f32
    float inv[4];
#pragma unroll
    for (int r = 0; r < 4; ++r) inv[r] = 1.0f / lrow[r];
    _Float16* op = part + bid * 8192 + ((w * 16 + fq * 4) << 7) + fr;
#pragma unroll
    for (int dt = 0; dt < 8; ++dt)
#pragma unroll
        for (int r = 0; r < 4; ++r)
            op[r * 128 + dt * 16] = (_Float16)(acc[dt][r] * inv[r]);
    if (fr == 0) {
#pragma unroll
        for (int r = 0; r < 4; ++r) {
            int ridx = bid * 64 + w * 16 + fq * 4 + r;
            stats[ridx * 2]     = mrow[r];
            stats[ridx * 2 + 1] = lrow[r];
        }
    }
#undef LOAD_TILE
#undef WRITE_TILE
}

// ---------------- kernel 3: combine split-KV partials ----------------
// 256 blocks (b,qt) x 256 threads. thread: row = t>>2, cols (t&3)*32..+32
__global__ __launch_bounds__(256) void comb_k(const _Float16* __restrict__ part,
                                              const float* __restrict__ stats,
                                              float* __restrict__ out) {
    int bid = blockIdx.x;
    int b = bid >> 5, qt = bid & 31;
    int G = qt >> 2;
    int base = b * 144 + qt + 2 * G * (G - 1) + (qt & 3) * G;
    int nc = G + 1;
    int t = threadIdx.x;
    int row = t >> 2, g = t & 3;

    float mstar = -1e30f;
    float mv[8], lv[8];
#pragma unroll
    for (int cc = 0; cc < 8; ++cc) {
        if (cc < nc) {
            mv[cc] = stats[((base + cc) * 64 + row) * 2];
            lv[cc] = stats[((base + cc) * 64 + row) * 2 + 1];
            mstar = fmaxf(mstar, mv[cc]);
        }
    }
    float den = 0.f, wc[8];
#pragma unroll
    for (int cc = 0; cc < 8; ++cc) {
        if (cc < nc) { wc[cc] = __expf(mv[cc] - mstar) * lv[cc]; den += wc[cc]; }
        else wc[cc] = 0.f;
    }
    float a[32] = {};
#pragma unroll
    for (int cc = 0; cc < 8; ++cc) {
        if (cc < nc) {
            const _Float16* pp = part + (base + cc) * 8192 + row * 128 + g * 32;
            float wcc = wc[cc];
#pragma unroll
            for (int u = 0; u < 4; ++u) {
                half8 h = *(const half8*)(pp + u * 8);
#pragma unroll
                for (int e = 0; e < 8; ++e) a[u * 8 + e] += wcc * (float)h[e];
            }
        }
    }
    float id = 1.0f / den;
    float* op = out + (b * 2048 + qt * 64 + row) * 128 + g * 32;
#pragma unroll
    for (int u = 0; u < 8; ++u) {
        float4 o;
        o.x = a[u * 4]     * id;
        o.y = a[u * 4 + 1] * id;
        o.z = a[u * 4 + 2] * id;
        o.w = a[u * 4 + 3] * id;
        *(float4*)(op + u * 4) = o;
    }
}

extern "C" void kernel_launch(void* const* d_in, const int* in_sizes, int n_in,
                              void* d_out, int out_size, void* d_ws, size_t ws_size,
                              hipStream_t stream) {
    const float* x  = (const float*)d_in[0];
    const float* wq = (const float*)d_in[1];
    const float* wk = (const float*)d_in[2];
    const float* wv = (const float*)d_in[3];

    char* ws = (char*)d_ws;
    _Float16* wh   = (_Float16*)(ws);                    // 768 KB
    _Float16* qhp  = (_Float16*)(ws + (1u  << 20));      // 4 MB
    _Float16* khp  = (_Float16*)(ws + (5u  << 20));      // 4 MB
    _Float16* vtp  = (_Float16*)(ws + (9u  << 20));      // 4 MB
    _Float16* part = (_Float16*)(ws + (13u << 20));      // 1152*16KB = 18.9 MB
    float*    stat = (float*)   (ws + (33u << 20));      // 590 KB

    wconv_k<<<192, 256, 0, stream>>>(wq, wk, wv, wh);
    qkv_k<<<512, 256, 0, stream>>>(x, wh, qhp, khp, vtp);
    attn_k<<<1152, 256, 0, stream>>>(qhp, khp, vtp, part, stat);
    comb_k<<<256, 256, 0, stream>>>(part, stat, (float*)d_out);
}